// Round 14
// baseline (407.478 us; speedup 1.0000x reference)
//
#include <hip/hip_runtime.h>
#include <hip/hip_bf16.h>
#include <stdint.h>

typedef __bf16 bf16;
typedef bf16 bf16x8 __attribute__((ext_vector_type(8)));
typedef float f32x4 __attribute__((ext_vector_type(4)));

#define B_ 2
#define L_ 2046
#define H_ 16
#define NW_ 682
#define LP_ 2048
#define NWP_ 704
#define M_ (B_*L_)
#define SCALE_ 0.125f
#define VTP 280   // vt row stride (bf16): 560B rows, 16B-aligned, ~2-way banks

__device__ inline bf16x8 zf8() {
  bf16x8 v;
#pragma unroll
  for (int e = 0; e < 8; ++e) v[e] = (bf16)0.0f;
  return v;
}

__device__ inline uint32_t pkbf(float a, float b) {
  uint16_t ua = __builtin_bit_cast(uint16_t, (bf16)a);
  uint16_t ub = __builtin_bit_cast(uint16_t, (bf16)b);
  return (uint32_t)ua | ((uint32_t)ub << 16);
}
__device__ inline float upk_lo(uint32_t u) { return __builtin_bit_cast(float, u << 16); }
__device__ inline float upk_hi(uint32_t u) { return __builtin_bit_cast(float, u & 0xffff0000u); }

// ---------------- cast f32 -> bf16 (vectorized x4) ----------------
__global__ __launch_bounds__(256) void cast4(const float* __restrict__ in,
                                             bf16* __restrict__ out, int n) {
  int i = (blockIdx.x * 256 + threadIdx.x) * 4;
  if (i + 3 < n) {
    float4 v = *reinterpret_cast<const float4*>(in + i);
    bf16 tmp[4];
    tmp[0] = (bf16)v.x; tmp[1] = (bf16)v.y; tmp[2] = (bf16)v.z; tmp[3] = (bf16)v.w;
    *reinterpret_cast<uint64_t*>(out + i) = *reinterpret_cast<const uint64_t*>(tmp);
  } else {
    for (; i < n; ++i) out[i] = (bf16)in[i];
  }
}

// ---------------- q = x @ Wq^T + bq : LDS-tiled MFMA GEMM (64x128 tile, BK=32) ----------------
__global__ __launch_bounds__(256) void qgemm_t(const bf16* __restrict__ X,
                                               const bf16* __restrict__ W,
                                               const float* __restrict__ bq,
                                               bf16* __restrict__ Q) {
  __shared__ bf16 As[64 * 40];    // [row][k] rows padded to 40 bf16 (80B)
  __shared__ bf16 Bs[128 * 40];
  int t = threadIdx.x, lane = t & 63, w = t >> 6;
  int lid = lane & 15, g = lane >> 4;
  int m0 = blockIdx.x * 64, n0 = blockIdx.y * 128;
  int wm = (w >> 1) * 32, wn = (w & 1) * 64;
  f32x4 z4 = {0.f, 0.f, 0.f, 0.f};
  f32x4 acc[2][4];
#pragma unroll
  for (int mi = 0; mi < 2; ++mi)
#pragma unroll
    for (int ni = 0; ni < 4; ++ni) acc[mi][ni] = z4;
  int r1 = t >> 2, c1 = t & 3;    // staging: row = r1 (0..63), 8-elem chunk c1 (0..3)
  for (int k0 = 0; k0 < 1024; k0 += 32) {
    int ga = m0 + r1; if (ga >= M_) ga = M_ - 1;
    bf16x8 av = *reinterpret_cast<const bf16x8*>(X + (size_t)ga * 1024 + k0 + c1 * 8);
    bf16x8 bv1 = *reinterpret_cast<const bf16x8*>(W + (size_t)(n0 + r1) * 1024 + k0 + c1 * 8);
    bf16x8 bv2 = *reinterpret_cast<const bf16x8*>(W + (size_t)(n0 + 64 + r1) * 1024 + k0 + c1 * 8);
    __syncthreads();   // previous tile fully consumed
    *reinterpret_cast<bf16x8*>(As + r1 * 40 + c1 * 8) = av;
    *reinterpret_cast<bf16x8*>(Bs + r1 * 40 + c1 * 8) = bv1;
    *reinterpret_cast<bf16x8*>(Bs + (64 + r1) * 40 + c1 * 8) = bv2;
    __syncthreads();
    bf16x8 af[2], bfr[4];
#pragma unroll
    for (int mi = 0; mi < 2; ++mi)
      af[mi] = *reinterpret_cast<const bf16x8*>(As + (wm + mi * 16 + lid) * 40 + g * 8);
#pragma unroll
    for (int ni = 0; ni < 4; ++ni)
      bfr[ni] = *reinterpret_cast<const bf16x8*>(Bs + (wn + ni * 16 + lid) * 40 + g * 8);
#pragma unroll
    for (int mi = 0; mi < 2; ++mi)
#pragma unroll
      for (int ni = 0; ni < 4; ++ni)
        acc[mi][ni] = __builtin_amdgcn_mfma_f32_16x16x32_bf16(af[mi], bfr[ni], acc[mi][ni], 0, 0, 0);
  }
  float bias[4];
#pragma unroll
  for (int ni = 0; ni < 4; ++ni) bias[ni] = bq[n0 + wn + ni * 16 + lid];
#pragma unroll
  for (int mi = 0; mi < 2; ++mi)
#pragma unroll
    for (int r = 0; r < 4; ++r) {
      int row = m0 + wm + mi * 16 + g * 4 + r;
      if (row < M_) {
#pragma unroll
        for (int ni = 0; ni < 4; ++ni)
          Q[(size_t)row * 1024 + n0 + wn + ni * 16 + lid] = (bf16)(acc[mi][ni][r] + bias[ni]);
      }
    }
}

// ---------------- global-head K/V projections (f32 math, bf16 row-major out) ----------------
__global__ __launch_bounds__(256) void proj_g32(const float* __restrict__ x,
    const float* __restrict__ Wk, const float* __restrict__ bk,
    const float* __restrict__ Wv, const float* __restrict__ bv,
    bf16* __restrict__ KGP, bf16* __restrict__ VGP) {
  __shared__ float xs[64][64];
  __shared__ float wks[64][65];
  __shared__ float wvs[64][65];
  int t = threadIdx.x;
  int lb = blockIdx.x, bh = blockIdx.y;
  int b = bh >> 3, h = bh & 7;
  int l0 = lb * 64;
  for (int idx = t; idx < 4096; idx += 256) {
    int r = idx >> 6, c = idx & 63;
    int l = l0 + r;
    xs[r][c] = (l < L_) ? x[((size_t)b * L_ + l) * 1024 + h * 64 + c] : 0.0f;
    wks[r][c] = Wk[(size_t)h * 4096 + idx];
    wvs[r][c] = Wv[(size_t)h * 4096 + idx];
  }
  __syncthreads();
  int o = t & 63, lg = t >> 6;
  float kbias = bk[h * 64 + o], vbias = bv[h * 64 + o];
  const size_t outb = (size_t)bh * LP_ * 64;
  for (int ls = 0; ls < 16; ++ls) {
    int l = lg * 16 + ls;
    float ka = kbias, va = vbias;
#pragma unroll
    for (int i = 0; i < 64; ++i) {
      float xv = xs[l][i];
      ka = fmaf(xv, wks[o][i], ka);
      va = fmaf(xv, wvs[o][i], va);
    }
    KGP[outb + (size_t)(l0 + l) * 64 + o] = (bf16)ka;
    VGP[outb + (size_t)(l0 + l) * 64 + o] = (bf16)va;
  }
}

// ---------------- local-head window-avg + K/V projections (f32 math, bf16 out) ----------------
__global__ __launch_bounds__(256) void proj_l32(const float* __restrict__ x,
    const float* __restrict__ Wk, const float* __restrict__ bk,
    const float* __restrict__ Wv, const float* __restrict__ bv,
    bf16* __restrict__ KLP, bf16* __restrict__ VLP) {
  __shared__ float xs[64][64];
  __shared__ float wks[64][65];
  __shared__ float wvs[64][65];
  int t = threadIdx.x;
  int nb = blockIdx.x, bh = blockIdx.y;
  int b = bh >> 3, h = bh & 7;
  int n0 = nb * 64;
  int hh = 8 + h;
  for (int idx = t; idx < 4096; idx += 256) {
    int r = idx >> 6, c = idx & 63;
    int n = n0 + r;
    float v = 0.0f;
    if (n < NW_) {
      size_t base = ((size_t)b * L_ + 3 * n) * 1024 + hh * 64 + c;
      v = (x[base] + x[base + 1024] + x[base + 2048]) * (1.0f / 3.0f);
    }
    xs[r][c] = v;
    wks[r][c] = Wk[(size_t)hh * 4096 + idx];
    wvs[r][c] = Wv[(size_t)hh * 4096 + idx];
  }
  __syncthreads();
  int o = t & 63, lg = t >> 6;
  float kbias = bk[hh * 64 + o], vbias = bv[hh * 64 + o];
  const size_t outb = (size_t)bh * NWP_ * 64;
  for (int ls = 0; ls < 16; ++ls) {
    int l = lg * 16 + ls;
    float ka = kbias, va = vbias;
#pragma unroll
    for (int i = 0; i < 64; ++i) {
      float xv = xs[l][i];
      ka = fmaf(xv, wks[o][i], ka);
      va = fmaf(xv, wvs[o][i], va);
    }
    KLP[outb + (size_t)(n0 + l) * 64 + o] = (bf16)ka;
    VLP[outb + (size_t)(n0 + l) * 64 + o] = (bf16)va;
  }
}

// ---------------- mask precompute: bit-packed (1 = masked) — R3-verified ----------------
__global__ __launch_bounds__(256) void maskprep(const float* __restrict__ mask,
                                                uint64_t* __restrict__ gm,
                                                uint64_t* __restrict__ wm) {
  int row = blockIdx.x * 4 + (threadIdx.x >> 6);  // b*L + l
  int lane = threadIdx.x & 63;
  if (row >= B_ * L_) return;
  int b = row / L_, l = row % L_;
  const float* mr = mask + (size_t)b * L_ * L_ + (size_t)l * L_;
  for (int w = 0; w < 32; ++w) {
    int m = w * 64 + lane;
    bool masked = (m >= L_) ? true : (mr[m] == 0.0f);
    uint64_t bal = __ballot(masked);
    if (lane == 0) gm[(size_t)row * 32 + w] = bal;
  }
  for (int w = 0; w < 11; ++w) {
    int n = w * 64 + lane;
    bool lmask = true;
    if (n < NW_) {
      float s = mr[3 * n] + mr[3 * n + 1] + mr[3 * n + 2];
      lmask = !(s >= 2.0f);
    }
    uint64_t bal = __ballot(lmask);
    if (lane == 0) wm[(size_t)row * 11 + w] = bal;
  }
}

// ---------------- FUSED global, 8-wave blocks: QK^T -> softmax -> pg + PV -> value ----------------
// LDS: strip 16x257 f32 (16.4K) + vt 64x280 bf16 (35.8K) + sums 0.5K ~= 53K
__global__ __launch_bounds__(512, 2) void attn_gf(const bf16* __restrict__ Q,
    const bf16* __restrict__ K, const bf16* __restrict__ V,
    const uint64_t* __restrict__ GM,
    float* __restrict__ OP, float* __restrict__ OV) {
  __shared__ float sums[128];
  __shared__ float strip[16][257];    // normalized P chunk (16 q-rows x 256 cols)
  __shared__ bf16 vt[64][VTP];        // shared V^T tile: [d][m_local 0..255]
  int t = threadIdx.x;
  int lane = t & 63, wave = t >> 6;   // 8 waves
  int lid = lane & 15, g = lane >> 4;
  int q0 = blockIdx.x * 16;
  int bh = blockIdx.y;
  int b = bh >> 3, h = bh & 7;
  const bf16* qb = Q + (size_t)b * L_ * 1024 + h * 64;
  const bf16* kb = K + (size_t)bh * LP_ * 64;
  const bf16* vpb = V + (size_t)bh * LP_ * 64;
  const uint64_t* gmb = GM + (size_t)b * L_ * 32;

  bf16x8 aq0 = zf8(), aq1 = zf8();
  {
    int qr = q0 + lid;
    if (qr < L_) {
      aq0 = *reinterpret_cast<const bf16x8*>(qb + (size_t)qr * 1024 + g * 8);
      aq1 = *reinterpret_cast<const bf16x8*>(qb + (size_t)qr * 1024 + 32 + g * 8);
    }
  }
  // ---- phase 1: single-pass QK^T, P in registers ----
  uint32_t preg[32];            // [it(8)][r(4)] packed (tt0, tt1) bf16 pair
  float rs[4] = {0.f, 0.f, 0.f, 0.f};
#pragma unroll
  for (int it = 0; it < 8; ++it) {
    int p = it * 8 + wave;
    int c0 = p * 32;
    int col0 = c0 + lid, col1 = c0 + 16 + lid;
    bf16x8 bka0 = *reinterpret_cast<const bf16x8*>(kb + (size_t)col0 * 64 + g * 8);
    bf16x8 bka1 = *reinterpret_cast<const bf16x8*>(kb + (size_t)col0 * 64 + 32 + g * 8);
    bf16x8 bkb0 = *reinterpret_cast<const bf16x8*>(kb + (size_t)col1 * 64 + g * 8);
    bf16x8 bkb1 = *reinterpret_cast<const bf16x8*>(kb + (size_t)col1 * 64 + 32 + g * 8);
    f32x4 acc0 = {0.f, 0.f, 0.f, 0.f}, acc1 = {0.f, 0.f, 0.f, 0.f};
    acc0 = __builtin_amdgcn_mfma_f32_16x16x32_bf16(aq0, bka0, acc0, 0, 0, 0);
    acc0 = __builtin_amdgcn_mfma_f32_16x16x32_bf16(aq1, bka1, acc0, 0, 0, 0);
    acc1 = __builtin_amdgcn_mfma_f32_16x16x32_bf16(aq0, bkb0, acc1, 0, 0, 0);
    acc1 = __builtin_amdgcn_mfma_f32_16x16x32_bf16(aq1, bkb1, acc1, 0, 0, 0);
    int wi = c0 >> 6;
    int bit0 = c0 & 32;
#pragma unroll
    for (int r = 0; r < 4; ++r) {
      int qr = q0 + g * 4 + r;
      uint64_t w = (qr < L_) ? gmb[(size_t)qr * 32 + wi] : ~0ull;
      float pv0 = ((w >> (bit0 + lid)) & 1) ? 0.0f : __expf(acc0[r] * SCALE_);
      float pv1 = ((w >> (bit0 + 16 + lid)) & 1) ? 0.0f : __expf(acc1[r] * SCALE_);
      rs[r] += pv0 + pv1;
      preg[it * 4 + r] = pkbf(pv0, pv1);
    }
  }
#pragma unroll
  for (int off = 8; off >= 1; off >>= 1)
#pragma unroll
    for (int r = 0; r < 4; ++r) rs[r] += __shfl_xor(rs[r], off, 64);
  if (lid == 0) {
#pragma unroll
    for (int r = 0; r < 4; ++r) sums[wave * 16 + g * 4 + r] = rs[r];
  }
  __syncthreads();
  float invr[4];
#pragma unroll
  for (int r = 0; r < 4; ++r) {
    int row = g * 4 + r;
    float s = 0.f;
#pragma unroll
    for (int ww = 0; ww < 8; ++ww) s += sums[ww * 16 + row];
    invr[r] = (s > 0.f) ? 1.0f / s : 0.0f;
  }
  // ---- phase 2: per 16x256 chunk: strip -> pg store + fused PV (shared vt) ----
  int orow = t >> 5;            // 0..15
  int qrT = q0 + orow;
  bool rowok = (qrT < L_);
  const size_t rowb = (size_t)bh * L_ * L_ + (size_t)(rowok ? qrT : 0) * L_;
  int c8 = (t & 31) * 8;
  int sd = t & 63, mq = t >> 6; // staging: d = sd, row-octet mq (0..7)
  f32x4 vacc[4];
  f32x4 z4 = {0.f, 0.f, 0.f, 0.f};
#pragma unroll
  for (int dg = 0; dg < 4; ++dg) vacc[dg] = z4;
#pragma unroll
  for (int it = 0; it < 8; ++it) {
    int mb0 = it * 256;
    // normalized strip write (own preg)
#pragma unroll
    for (int r = 0; r < 4; ++r) {
      uint32_t u = preg[it * 4 + r];
      strip[g * 4 + r][wave * 32 + lid] = upk_lo(u) * invr[r];
      strip[g * 4 + r][wave * 32 + 16 + lid] = upk_hi(u) * invr[r];
    }
    // cooperative V^T stage: 256 rows x 64 d
#pragma unroll
    for (int blk = 0; blk < 4; ++blk) {
      bf16 st[8];
#pragma unroll
      for (int e = 0; e < 8; ++e)
        st[e] = vpb[(size_t)(mb0 + blk * 64 + mq * 8 + e) * 64 + sd];
      *reinterpret_cast<bf16x8*>(&vt[sd][blk * 64 + mq * 8]) = *reinterpret_cast<const bf16x8*>(st);
    }
    __syncthreads();
    // coalesced pg store (8 floats/thread)
    int col = mb0 + c8;
    if (rowok) {
#pragma unroll
      for (int pr = 0; pr < 4; ++pr) {
        int cc = c8 + pr * 2;
        if (col + pr * 2 + 1 < L_) {
          float2 o2 = make_float2(strip[orow][cc], strip[orow][cc + 1]);
          *reinterpret_cast<float2*>(OP + rowb + col + pr * 2) = o2;
        }
      }
    }
    // PV: own-wave 32-col m-chunk
    bf16x8 af;
#pragma unroll
    for (int e = 0; e < 8; ++e) af[e] = (bf16)strip[lid][wave * 32 + g * 8 + e];
#pragma unroll
    for (int dg = 0; dg < 4; ++dg) {
      bf16x8 bv8 = *reinterpret_cast<const bf16x8*>(&vt[dg * 16 + lid][wave * 32 + g * 8]);
      vacc[dg] = __builtin_amdgcn_mfma_f32_16x16x32_bf16(af, bv8, vacc[dg], 0, 0, 0);
    }
    __syncthreads();
  }
  // ---- cross-wave OV reduce via strip (serialized adds) ----
#pragma unroll
  for (int wsel = 0; wsel < 8; ++wsel) {
    if (wave == wsel) {
#pragma unroll
      for (int dg = 0; dg < 4; ++dg)
#pragma unroll
        for (int r = 0; r < 4; ++r) {
          if (wsel == 0) strip[g * 4 + r][dg * 16 + lid] = vacc[dg][r];
          else           strip[g * 4 + r][dg * 16 + lid] += vacc[dg][r];
        }
    }
    __syncthreads();
  }
  float* ob = OV + (((size_t)b * 16 + h) * L_) * 64;
  for (int idx = t; idx < 1024; idx += 512) {
    int r = idx >> 6, d = idx & 63;
    int qr = q0 + r;
    if (qr < L_) ob[(size_t)qr * 64 + d] = strip[r][d];
  }
}

// ---------------- FUSED local, 8-wave blocks ----------------
__global__ __launch_bounds__(512, 2) void attn_lf(const bf16* __restrict__ Q,
    const bf16* __restrict__ K, const bf16* __restrict__ V,
    const uint64_t* __restrict__ WM,
    float* __restrict__ OP, float* __restrict__ OV) {
  __shared__ float sums[128];
  __shared__ float strip[16][257];
  __shared__ bf16 vt[64][VTP];
  int t = threadIdx.x;
  int lane = t & 63, wave = t >> 6;
  int lid = lane & 15, g = lane >> 4;
  int q0 = blockIdx.x * 16;
  int bh = blockIdx.y;
  int b = bh >> 3, h = bh & 7;
  const bf16* qb = Q + (size_t)b * L_ * 1024 + (8 + h) * 64;
  const bf16* kb = K + (size_t)bh * NWP_ * 64;
  const bf16* vpb = V + (size_t)bh * NWP_ * 64;
  const uint64_t* wmb = WM + (size_t)b * L_ * 11;

  bf16x8 aq0 = zf8(), aq1 = zf8();
  {
    int qr = q0 + lid;
    if (qr < L_) {
      aq0 = *reinterpret_cast<const bf16x8*>(qb + (size_t)qr * 1024 + g * 8);
      aq1 = *reinterpret_cast<const bf16x8*>(qb + (size_t)qr * 1024 + 32 + g * 8);
    }
  }
  uint32_t preg[12];
  float rs[4] = {0.f, 0.f, 0.f, 0.f};
#pragma unroll
  for (int it = 0; it < 3; ++it) {
    int p = it * 8 + wave;
    if (p < 22) {
      int c0 = p * 32;
      int col0 = c0 + lid, col1 = c0 + 16 + lid;
      bf16x8 bka0 = *reinterpret_cast<const bf16x8*>(kb + (size_t)col0 * 64 + g * 8);
      bf16x8 bka1 = *reinterpret_cast<const bf16x8*>(kb + (size_t)col0 * 64 + 32 + g * 8);
      bf16x8 bkb0 = *reinterpret_cast<const bf16x8*>(kb + (size_t)col1 * 64 + g * 8);
      bf16x8 bkb1 = *reinterpret_cast<const bf16x8*>(kb + (size_t)col1 * 64 + 32 + g * 8);
      f32x4 acc0 = {0.f, 0.f, 0.f, 0.f}, acc1 = {0.f, 0.f, 0.f, 0.f};
      acc0 = __builtin_amdgcn_mfma_f32_16x16x32_bf16(aq0, bka0, acc0, 0, 0, 0);
      acc0 = __builtin_amdgcn_mfma_f32_16x16x32_bf16(aq1, bka1, acc0, 0, 0, 0);
      acc1 = __builtin_amdgcn_mfma_f32_16x16x32_bf16(aq0, bkb0, acc1, 0, 0, 0);
      acc1 = __builtin_amdgcn_mfma_f32_16x16x32_bf16(aq1, bkb1, acc1, 0, 0, 0);
      int wi = c0 >> 6;
      int bit0 = c0 & 32;
#pragma unroll
      for (int r = 0; r < 4; ++r) {
        int qr = q0 + g * 4 + r;
        uint64_t w = (qr < L_) ? wmb[(size_t)qr * 11 + wi] : ~0ull;
        float pv0 = ((w >> (bit0 + lid)) & 1) ? 0.0f : __expf(acc0[r] * SCALE_);
        float pv1 = ((w >> (bit0 + 16 + lid)) & 1) ? 0.0f : __expf(acc1[r] * SCALE_);
        rs[r] += pv0 + pv1;
        preg[it * 4 + r] = pkbf(pv0, pv1);
      }
    }
  }
#pragma unroll
  for (int off = 8; off >= 1; off >>= 1)
#pragma unroll
    for (int r = 0; r < 4; ++r) rs[r] += __shfl_xor(rs[r], off, 64);
  if (lid == 0) {
#pragma unroll
    for (int r = 0; r < 4; ++r) sums[wave * 16 + g * 4 + r] = rs[r];
  }
  __syncthreads();
  float invr[4];
#pragma unroll
  for (int r = 0; r < 4; ++r) {
    int row = g * 4 + r;
    float s = 0.f;
#pragma unroll
    for (int ww = 0; ww < 8; ++ww) s += sums[ww * 16 + row];
    invr[r] = (s > 0.f) ? 1.0f / s : 0.0f;
  }
  int orow = t >> 5;
  int qrT = q0 + orow;
  bool rowok = (qrT < L_);
  const size_t rowb = (size_t)bh * L_ * NW_ + (size_t)(rowok ? qrT : 0) * NW_;
  int c8 = (t & 31) * 8;
  int sd = t & 63, mq = t >> 6;
  f32x4 vacc[4];
  f32x4 z4 = {0.f, 0.f, 0.f, 0.f};
#pragma unroll
  for (int dg = 0; dg < 4; ++dg) vacc[dg] = z4;
#pragma unroll
  for (int it = 0; it < 3; ++it) {
    int p = it * 8 + wave;
    bool act = (p < 22);
    int mb0 = it * 256;
    if (act) {
#pragma unroll
      for (int r = 0; r < 4; ++r) {
        uint32_t u = preg[it * 4 + r];
        strip[g * 4 + r][wave * 32 + lid] = upk_lo(u) * invr[r];
        strip[g * 4 + r][wave * 32 + 16 + lid] = upk_hi(u) * invr[r];
      }
    }
    // cooperative V^T stage (rows clamped to NWP_; masked cols have P=0)
#pragma unroll
    for (int blk = 0; blk < 4; ++blk) {
      bf16 st[8];
#pragma unroll
      for (int e = 0; e < 8; ++e) {
        int m = mb0 + blk * 64 + mq * 8 + e;
        if (m >= NWP_) m = NWP_ - 1;
        st[e] = vpb[(size_t)m * 64 + sd];
      }
      *reinterpret_cast<bf16x8*>(&vt[sd][blk * 64 + mq * 8]) = *reinterpret_cast<const bf16x8*>(st);
    }
    __syncthreads();
    int col = mb0 + c8;
    if (rowok) {
#pragma unroll
      for (int pr = 0; pr < 4; ++pr) {
        int cc = c8 + pr * 2;
        if (col + pr * 2 + 1 < NW_) {
          float2 o2 = make_float2(strip[orow][cc], strip[orow][cc + 1]);
          *reinterpret_cast<float2*>(OP + rowb + col + pr * 2) = o2;
        }
      }
    }
    if (act) {
      bf16x8 af;
#pragma unroll
      for (int e = 0; e < 8; ++e) af[e] = (bf16)strip[lid][wave * 32 + g * 8 + e];
#pragma unroll
      for (int dg = 0; dg < 4; ++dg) {
        bf16x8 bv8 = *reinterpret_cast<const bf16x8*>(&vt[dg * 16 + lid][wave * 32 + g * 8]);
        vacc[dg] = __builtin_amdgcn_mfma_f32_16x16x32_bf16(af, bv8, vacc[dg], 0, 0, 0);
      }
    }
    __syncthreads();
  }
#pragma unroll
  for (int wsel = 0; wsel < 8; ++wsel) {
    if (wave == wsel) {
#pragma unroll
      for (int dg = 0; dg < 4; ++dg)
#pragma unroll
        for (int r = 0; r < 4; ++r) {
          if (wsel == 0) strip[g * 4 + r][dg * 16 + lid] = vacc[dg][r];
          else           strip[g * 4 + r][dg * 16 + lid] += vacc[dg][r];
        }
    }
    __syncthreads();
  }
  float* ob = OV + (((size_t)b * 16 + 8 + h) * L_) * 64;
  for (int idx = t; idx < 1024; idx += 512) {
    int r = idx >> 6, d = idx & 63;
    int qr = q0 + r;
    if (qr < L_) ob[(size_t)qr * 64 + d] = strip[r][d];
  }
}

extern "C" void kernel_launch(void* const* d_in, const int* in_sizes, int n_in,
                              void* d_out, int out_size, void* d_ws, size_t ws_size,
                              hipStream_t stream) {
  (void)in_sizes; (void)n_in; (void)out_size; (void)ws_size;
  const float* x    = (const float*)d_in[0];
  const float* mask = (const float*)d_in[1];
  const float* Wq   = (const float*)d_in[2];
  const float* bq   = (const float*)d_in[3];
  const float* Wk   = (const float*)d_in[4];
  const float* bk   = (const float*)d_in[5];
  const float* Wv   = (const float*)d_in[6];
  const float* bv   = (const float*)d_in[7];

  char* ws = (char*)d_ws;
  bf16* qbb     = (bf16*)(ws + 0);            // 8,380,416
  bf16* kgb     = (bf16*)(ws + 8380416);      // 4,194,304
  bf16* vgb     = (bf16*)(ws + 12574720);     // 4,194,304 (row-major V)
  bf16* klb     = (bf16*)(ws + 16769024);     // 1,441,792
  bf16* vlb     = (bf16*)(ws + 18210816);     // 1,441,792
  uint64_t* gm  = (uint64_t*)(ws + 19652608); // 1,047,552
  uint64_t* wm  = (uint64_t*)(ws + 20700160); // 360,096
  bf16* xbb     = (bf16*)(ws + 21060256);     // 8,380,416 (x in bf16)
  bf16* wqb     = (bf16*)(ws + 29440672);     // 2,097,152 (Wq in bf16)

  float* out    = (float*)d_out;
  float* o_vall = out;                 // (2,16,2046,64)
  float* o_pg   = out + 4190208;       // (2,8,2046,2046)
  float* o_pl   = out + 71168064;      // (2,8,2046,682)

  cast4<<<4092, 256, 0, stream>>>(x, xbb, 4190208);
  cast4<<<1024, 256, 0, stream>>>(Wq, wqb, 1048576);
  qgemm_t<<<dim3(64, 8), 256, 0, stream>>>(xbb, wqb, bq, qbb);
  proj_g32<<<dim3(32, 16), 256, 0, stream>>>(x, Wk, bk, Wv, bv, kgb, vgb);
  proj_l32<<<dim3(11, 16), 256, 0, stream>>>(x, Wk, bk, Wv, bv, klb, vlb);
  maskprep<<<1023, 256, 0, stream>>>(mask, gm, wm);

  attn_gf<<<dim3(128, 16), 512, 0, stream>>>(qbb, kgb, vgb, gm, o_pg, o_vall);
  attn_lf<<<dim3(128, 16), 512, 0, stream>>>(qbb, klb, vlb, wm, o_pl, o_vall);
}

// Round 15
// 392.872 us; speedup vs baseline: 1.0372x; 1.0372x over previous
//
#include <hip/hip_runtime.h>
#include <hip/hip_bf16.h>
#include <stdint.h>

typedef __bf16 bf16;
typedef bf16 bf16x8 __attribute__((ext_vector_type(8)));
typedef float f32x4 __attribute__((ext_vector_type(4)));

#define B_ 2
#define L_ 2046
#define H_ 16
#define NW_ 682
#define LP_ 2048
#define NWP_ 704
#define M_ (B_*L_)
#define SCALE_ 0.125f

__device__ inline bf16x8 zf8() {
  bf16x8 v;
#pragma unroll
  for (int e = 0; e < 8; ++e) v[e] = (bf16)0.0f;
  return v;
}

__device__ inline uint32_t pkbf(float a, float b) {
  uint16_t ua = __builtin_bit_cast(uint16_t, (bf16)a);
  uint16_t ub = __builtin_bit_cast(uint16_t, (bf16)b);
  return (uint32_t)ua | ((uint32_t)ub << 16);
}
__device__ inline float upk_lo(uint32_t u) { return __builtin_bit_cast(float, u << 16); }
__device__ inline float upk_hi(uint32_t u) { return __builtin_bit_cast(float, u & 0xffff0000u); }

// ---------------- cast f32 -> bf16 (vectorized x4) ----------------
__global__ __launch_bounds__(256) void cast4(const float* __restrict__ in,
                                             bf16* __restrict__ out, int n) {
  int i = (blockIdx.x * 256 + threadIdx.x) * 4;
  if (i + 3 < n) {
    float4 v = *reinterpret_cast<const float4*>(in + i);
    bf16 tmp[4];
    tmp[0] = (bf16)v.x; tmp[1] = (bf16)v.y; tmp[2] = (bf16)v.z; tmp[3] = (bf16)v.w;
    *reinterpret_cast<uint64_t*>(out + i) = *reinterpret_cast<const uint64_t*>(tmp);
  } else {
    for (; i < n; ++i) out[i] = (bf16)in[i];
  }
}

// ---------------- q = x @ Wq^T + bq : LDS-tiled MFMA GEMM (64x128 tile, BK=32) ----------------
__global__ __launch_bounds__(256) void qgemm_t(const bf16* __restrict__ X,
                                               const bf16* __restrict__ W,
                                               const float* __restrict__ bq,
                                               bf16* __restrict__ Q) {
  __shared__ bf16 As[64 * 40];    // [row][k] rows padded to 40 bf16 (80B)
  __shared__ bf16 Bs[128 * 40];
  int t = threadIdx.x, lane = t & 63, w = t >> 6;
  int lid = lane & 15, g = lane >> 4;
  int m0 = blockIdx.x * 64, n0 = blockIdx.y * 128;
  int wm = (w >> 1) * 32, wn = (w & 1) * 64;
  f32x4 z4 = {0.f, 0.f, 0.f, 0.f};
  f32x4 acc[2][4];
#pragma unroll
  for (int mi = 0; mi < 2; ++mi)
#pragma unroll
    for (int ni = 0; ni < 4; ++ni) acc[mi][ni] = z4;
  int r1 = t >> 2, c1 = t & 3;    // staging: row = r1 (0..63), 8-elem chunk c1 (0..3)
  for (int k0 = 0; k0 < 1024; k0 += 32) {
    int ga = m0 + r1; if (ga >= M_) ga = M_ - 1;
    bf16x8 av = *reinterpret_cast<const bf16x8*>(X + (size_t)ga * 1024 + k0 + c1 * 8);
    bf16x8 bv1 = *reinterpret_cast<const bf16x8*>(W + (size_t)(n0 + r1) * 1024 + k0 + c1 * 8);
    bf16x8 bv2 = *reinterpret_cast<const bf16x8*>(W + (size_t)(n0 + 64 + r1) * 1024 + k0 + c1 * 8);
    __syncthreads();   // previous tile fully consumed
    *reinterpret_cast<bf16x8*>(As + r1 * 40 + c1 * 8) = av;
    *reinterpret_cast<bf16x8*>(Bs + r1 * 40 + c1 * 8) = bv1;
    *reinterpret_cast<bf16x8*>(Bs + (64 + r1) * 40 + c1 * 8) = bv2;
    __syncthreads();
    bf16x8 af[2], bfr[4];
#pragma unroll
    for (int mi = 0; mi < 2; ++mi)
      af[mi] = *reinterpret_cast<const bf16x8*>(As + (wm + mi * 16 + lid) * 40 + g * 8);
#pragma unroll
    for (int ni = 0; ni < 4; ++ni)
      bfr[ni] = *reinterpret_cast<const bf16x8*>(Bs + (wn + ni * 16 + lid) * 40 + g * 8);
#pragma unroll
    for (int mi = 0; mi < 2; ++mi)
#pragma unroll
      for (int ni = 0; ni < 4; ++ni)
        acc[mi][ni] = __builtin_amdgcn_mfma_f32_16x16x32_bf16(af[mi], bfr[ni], acc[mi][ni], 0, 0, 0);
  }
  float bias[4];
#pragma unroll
  for (int ni = 0; ni < 4; ++ni) bias[ni] = bq[n0 + wn + ni * 16 + lid];
#pragma unroll
  for (int mi = 0; mi < 2; ++mi)
#pragma unroll
    for (int r = 0; r < 4; ++r) {
      int row = m0 + wm + mi * 16 + g * 4 + r;
      if (row < M_) {
#pragma unroll
        for (int ni = 0; ni < 4; ++ni)
          Q[(size_t)row * 1024 + n0 + wn + ni * 16 + lid] = (bf16)(acc[mi][ni][r] + bias[ni]);
      }
    }
}

// ---------------- global-head K/V projections; K row-major, V TRANSPOSED out ----------------
__global__ __launch_bounds__(256) void proj_g32(const float* __restrict__ x,
    const float* __restrict__ Wk, const float* __restrict__ bk,
    const float* __restrict__ Wv, const float* __restrict__ bv,
    bf16* __restrict__ KGP, bf16* __restrict__ VGT) {
  __shared__ float xs[64][64];
  __shared__ float wks[64][65];
  __shared__ float wvs[64][65];
  int t = threadIdx.x;
  int lb = blockIdx.x, bh = blockIdx.y;
  int b = bh >> 3, h = bh & 7;
  int l0 = lb * 64;
  for (int idx = t; idx < 4096; idx += 256) {
    int r = idx >> 6, c = idx & 63;
    int l = l0 + r;
    xs[r][c] = (l < L_) ? x[((size_t)b * L_ + l) * 1024 + h * 64 + c] : 0.0f;
    wks[r][c] = Wk[(size_t)h * 4096 + idx];
    wvs[r][c] = Wv[(size_t)h * 4096 + idx];
  }
  __syncthreads();
  int o = t & 63, lg = t >> 6;
  float kbias = bk[h * 64 + o], vbias = bv[h * 64 + o];
  float vacc[16];
  const size_t outb = (size_t)bh * LP_ * 64;
  for (int ls = 0; ls < 16; ++ls) {
    int l = lg * 16 + ls;
    float ka = kbias, va = vbias;
#pragma unroll
    for (int i = 0; i < 64; ++i) {
      float xv = xs[l][i];
      ka = fmaf(xv, wks[o][i], ka);
      va = fmaf(xv, wvs[o][i], va);
    }
    KGP[outb + (size_t)(l0 + l) * 64 + o] = (bf16)ka;
    vacc[ls] = va;
  }
  __syncthreads();   // wvs free
#pragma unroll
  for (int ls = 0; ls < 16; ++ls) wvs[o][lg * 16 + ls] = vacc[ls];
  __syncthreads();
  for (int idx = t; idx < 4096; idx += 256) {
    int oo = idx >> 6, ll = idx & 63;
    VGT[(size_t)bh * 64 * LP_ + (size_t)oo * LP_ + l0 + ll] = (bf16)wvs[oo][ll];
  }
}

// ---------------- local-head window-avg + K/V projections; V TRANSPOSED out ----------------
__global__ __launch_bounds__(256) void proj_l32(const float* __restrict__ x,
    const float* __restrict__ Wk, const float* __restrict__ bk,
    const float* __restrict__ Wv, const float* __restrict__ bv,
    bf16* __restrict__ KLP, bf16* __restrict__ VLT) {
  __shared__ float xs[64][64];
  __shared__ float wks[64][65];
  __shared__ float wvs[64][65];
  int t = threadIdx.x;
  int nb = blockIdx.x, bh = blockIdx.y;
  int b = bh >> 3, h = bh & 7;
  int n0 = nb * 64;
  int hh = 8 + h;
  for (int idx = t; idx < 4096; idx += 256) {
    int r = idx >> 6, c = idx & 63;
    int n = n0 + r;
    float v = 0.0f;
    if (n < NW_) {
      size_t base = ((size_t)b * L_ + 3 * n) * 1024 + hh * 64 + c;
      v = (x[base] + x[base + 1024] + x[base + 2048]) * (1.0f / 3.0f);
    }
    xs[r][c] = v;
    wks[r][c] = Wk[(size_t)hh * 4096 + idx];
    wvs[r][c] = Wv[(size_t)hh * 4096 + idx];
  }
  __syncthreads();
  int o = t & 63, lg = t >> 6;
  float kbias = bk[hh * 64 + o], vbias = bv[hh * 64 + o];
  float vacc[16];
  const size_t outb = (size_t)bh * NWP_ * 64;
  for (int ls = 0; ls < 16; ++ls) {
    int l = lg * 16 + ls;
    float ka = kbias, va = vbias;
#pragma unroll
    for (int i = 0; i < 64; ++i) {
      float xv = xs[l][i];
      ka = fmaf(xv, wks[o][i], ka);
      va = fmaf(xv, wvs[o][i], va);
    }
    KLP[outb + (size_t)(n0 + l) * 64 + o] = (bf16)ka;
    vacc[ls] = va;
  }
  __syncthreads();
#pragma unroll
  for (int ls = 0; ls < 16; ++ls) wvs[o][lg * 16 + ls] = vacc[ls];
  __syncthreads();
  for (int idx = t; idx < 4096; idx += 256) {
    int oo = idx >> 6, ll = idx & 63;
    VLT[(size_t)bh * 64 * NWP_ + (size_t)oo * NWP_ + n0 + ll] = (bf16)wvs[oo][ll];
  }
}

// ---------------- mask precompute: bit-packed (1 = masked) — R3-verified ----------------
__global__ __launch_bounds__(256) void maskprep(const float* __restrict__ mask,
                                                uint64_t* __restrict__ gm,
                                                uint64_t* __restrict__ wm) {
  int row = blockIdx.x * 4 + (threadIdx.x >> 6);  // b*L + l
  int lane = threadIdx.x & 63;
  if (row >= B_ * L_) return;
  int b = row / L_, l = row % L_;
  const float* mr = mask + (size_t)b * L_ * L_ + (size_t)l * L_;
  for (int w = 0; w < 32; ++w) {
    int m = w * 64 + lane;
    bool masked = (m >= L_) ? true : (mr[m] == 0.0f);
    uint64_t bal = __ballot(masked);
    if (lane == 0) gm[(size_t)row * 32 + w] = bal;
  }
  for (int w = 0; w < 11; ++w) {
    int n = w * 64 + lane;
    bool lmask = true;
    if (n < NW_) {
      float s = mr[3 * n] + mr[3 * n + 1] + mr[3 * n + 2];
      lmask = !(s >= 2.0f);
    }
    uint64_t bal = __ballot(lmask);
    if (lane == 0) wm[(size_t)row * 11 + w] = bal;
  }
}

// ---------------- FUSED global, 8-wave: QK^T -> softmax -> pg + PV (V^T direct) ----------------
// LDS: strip2 32.9K + sums 0.5K ~= 33.5K; no V tile.
__global__ __launch_bounds__(512, 2) void attn_gf(const bf16* __restrict__ Q,
    const bf16* __restrict__ K, const bf16* __restrict__ VT,
    const uint64_t* __restrict__ GM,
    float* __restrict__ OP, float* __restrict__ OV) {
  __shared__ float sums[128];
  __shared__ float strip2[2][16][257];
  int t = threadIdx.x;
  int lane = t & 63, wave = t >> 6;   // 8 waves
  int lid = lane & 15, g = lane >> 4;
  int q0 = blockIdx.x * 16;
  int bh = blockIdx.y;
  int b = bh >> 3, h = bh & 7;
  const bf16* qb = Q + (size_t)b * L_ * 1024 + h * 64;
  const bf16* kb = K + (size_t)bh * LP_ * 64;
  const bf16* vtg = VT + (size_t)bh * 64 * LP_;   // V^T [d][m]
  const uint64_t* gmb = GM + (size_t)b * L_ * 32;

  bf16x8 aq0 = zf8(), aq1 = zf8();
  {
    int qr = q0 + lid;
    if (qr < L_) {
      aq0 = *reinterpret_cast<const bf16x8*>(qb + (size_t)qr * 1024 + g * 8);
      aq1 = *reinterpret_cast<const bf16x8*>(qb + (size_t)qr * 1024 + 32 + g * 8);
    }
  }
  // ---- phase 1: single-pass QK^T, P in registers ----
  uint32_t preg[32];            // [it(8)][r(4)]
  float rs[4] = {0.f, 0.f, 0.f, 0.f};
#pragma unroll
  for (int it = 0; it < 8; ++it) {
    int p = it * 8 + wave;
    int c0 = p * 32;
    int col0 = c0 + lid, col1 = c0 + 16 + lid;
    bf16x8 bka0 = *reinterpret_cast<const bf16x8*>(kb + (size_t)col0 * 64 + g * 8);
    bf16x8 bka1 = *reinterpret_cast<const bf16x8*>(kb + (size_t)col0 * 64 + 32 + g * 8);
    bf16x8 bkb0 = *reinterpret_cast<const bf16x8*>(kb + (size_t)col1 * 64 + g * 8);
    bf16x8 bkb1 = *reinterpret_cast<const bf16x8*>(kb + (size_t)col1 * 64 + 32 + g * 8);
    f32x4 acc0 = {0.f, 0.f, 0.f, 0.f}, acc1 = {0.f, 0.f, 0.f, 0.f};
    acc0 = __builtin_amdgcn_mfma_f32_16x16x32_bf16(aq0, bka0, acc0, 0, 0, 0);
    acc0 = __builtin_amdgcn_mfma_f32_16x16x32_bf16(aq1, bka1, acc0, 0, 0, 0);
    acc1 = __builtin_amdgcn_mfma_f32_16x16x32_bf16(aq0, bkb0, acc1, 0, 0, 0);
    acc1 = __builtin_amdgcn_mfma_f32_16x16x32_bf16(aq1, bkb1, acc1, 0, 0, 0);
    int wi = c0 >> 6;
    int bit0 = c0 & 32;
#pragma unroll
    for (int r = 0; r < 4; ++r) {
      int qr = q0 + g * 4 + r;
      uint64_t w = (qr < L_) ? gmb[(size_t)qr * 32 + wi] : ~0ull;
      float pv0 = ((w >> (bit0 + lid)) & 1) ? 0.0f : __expf(acc0[r] * SCALE_);
      float pv1 = ((w >> (bit0 + 16 + lid)) & 1) ? 0.0f : __expf(acc1[r] * SCALE_);
      rs[r] += pv0 + pv1;
      preg[it * 4 + r] = pkbf(pv0, pv1);
    }
  }
#pragma unroll
  for (int off = 8; off >= 1; off >>= 1)
#pragma unroll
    for (int r = 0; r < 4; ++r) rs[r] += __shfl_xor(rs[r], off, 64);
  if (lid == 0) {
#pragma unroll
    for (int r = 0; r < 4; ++r) sums[wave * 16 + g * 4 + r] = rs[r];
  }
  __syncthreads();
  float invr[4];
#pragma unroll
  for (int r = 0; r < 4; ++r) {
    int row = g * 4 + r;
    float s = 0.f;
#pragma unroll
    for (int ww = 0; ww < 8; ++ww) s += sums[ww * 16 + row];
    invr[r] = (s > 0.f) ? 1.0f / s : 0.0f;
  }
  // ---- phase 2: ping-pong strip; pg store + PV from global V^T ----
  int orow = t >> 5;            // 0..15
  int qrT = q0 + orow;
  bool rowok = (qrT < L_);
  const size_t rowb = (size_t)bh * L_ * L_ + (size_t)(rowok ? qrT : 0) * L_;
  int c8 = (t & 31) * 8;
  f32x4 vacc[4];
  f32x4 z4 = {0.f, 0.f, 0.f, 0.f};
#pragma unroll
  for (int dg = 0; dg < 4; ++dg) vacc[dg] = z4;
#pragma unroll
  for (int it = 0; it < 8; ++it) {
    float* sbuf = &strip2[it & 1][0][0];
    int mb0 = it * 256;
#pragma unroll
    for (int r = 0; r < 4; ++r) {
      uint32_t u = preg[it * 4 + r];
      sbuf[(g * 4 + r) * 257 + wave * 32 + lid] = upk_lo(u) * invr[r];
      sbuf[(g * 4 + r) * 257 + wave * 32 + 16 + lid] = upk_hi(u) * invr[r];
    }
    __syncthreads();
    // coalesced pg store (8 floats/thread)
    int col = mb0 + c8;
    if (rowok) {
#pragma unroll
      for (int pr = 0; pr < 4; ++pr) {
        int cc = c8 + pr * 2;
        if (col + pr * 2 + 1 < L_) {
          float2 o2 = make_float2(sbuf[orow * 257 + cc], sbuf[orow * 257 + cc + 1]);
          *reinterpret_cast<float2*>(OP + rowb + col + pr * 2) = o2;
        }
      }
    }
    // PV: A from strip, B directly from global V^T
    bf16x8 af;
#pragma unroll
    for (int e = 0; e < 8; ++e) af[e] = (bf16)sbuf[lid * 257 + wave * 32 + g * 8 + e];
#pragma unroll
    for (int dg = 0; dg < 4; ++dg) {
      bf16x8 bv8 = *reinterpret_cast<const bf16x8*>(vtg + (size_t)(dg * 16 + lid) * LP_ + mb0 + wave * 32 + g * 8);
      vacc[dg] = __builtin_amdgcn_mfma_f32_16x16x32_bf16(af, bv8, vacc[dg], 0, 0, 0);
    }
  }
  __syncthreads();
  // ---- cross-wave OV reduce via strip2[0] ----
  float* red = &strip2[0][0][0];
#pragma unroll
  for (int wsel = 0; wsel < 8; ++wsel) {
    if (wave == wsel) {
#pragma unroll
      for (int dg = 0; dg < 4; ++dg)
#pragma unroll
        for (int r = 0; r < 4; ++r) {
          if (wsel == 0) red[(g * 4 + r) * 257 + dg * 16 + lid] = vacc[dg][r];
          else           red[(g * 4 + r) * 257 + dg * 16 + lid] += vacc[dg][r];
        }
    }
    __syncthreads();
  }
  float* ob = OV + (((size_t)b * 16 + h) * L_) * 64;
  for (int idx = t; idx < 1024; idx += 512) {
    int r = idx >> 6, d = idx & 63;
    int qr = q0 + r;
    if (qr < L_) ob[(size_t)qr * 64 + d] = red[r * 257 + d];
  }
}

// ---------------- FUSED local, 8-wave (V^T direct) ----------------
__global__ __launch_bounds__(512, 2) void attn_lf(const bf16* __restrict__ Q,
    const bf16* __restrict__ K, const bf16* __restrict__ VT,
    const uint64_t* __restrict__ WM,
    float* __restrict__ OP, float* __restrict__ OV) {
  __shared__ float sums[128];
  __shared__ float strip2[2][16][257];
  int t = threadIdx.x;
  int lane = t & 63, wave = t >> 6;
  int lid = lane & 15, g = lane >> 4;
  int q0 = blockIdx.x * 16;
  int bh = blockIdx.y;
  int b = bh >> 3, h = bh & 7;
  const bf16* qb = Q + (size_t)b * L_ * 1024 + (8 + h) * 64;
  const bf16* kb = K + (size_t)bh * NWP_ * 64;
  const bf16* vtg = VT + (size_t)bh * 64 * NWP_;
  const uint64_t* wmb = WM + (size_t)b * L_ * 11;

  bf16x8 aq0 = zf8(), aq1 = zf8();
  {
    int qr = q0 + lid;
    if (qr < L_) {
      aq0 = *reinterpret_cast<const bf16x8*>(qb + (size_t)qr * 1024 + g * 8);
      aq1 = *reinterpret_cast<const bf16x8*>(qb + (size_t)qr * 1024 + 32 + g * 8);
    }
  }
  uint32_t preg[12];
  float rs[4] = {0.f, 0.f, 0.f, 0.f};
#pragma unroll
  for (int it = 0; it < 3; ++it) {
    int p = it * 8 + wave;
    if (p < 22) {
      int c0 = p * 32;
      int col0 = c0 + lid, col1 = c0 + 16 + lid;
      bf16x8 bka0 = *reinterpret_cast<const bf16x8*>(kb + (size_t)col0 * 64 + g * 8);
      bf16x8 bka1 = *reinterpret_cast<const bf16x8*>(kb + (size_t)col0 * 64 + 32 + g * 8);
      bf16x8 bkb0 = *reinterpret_cast<const bf16x8*>(kb + (size_t)col1 * 64 + g * 8);
      bf16x8 bkb1 = *reinterpret_cast<const bf16x8*>(kb + (size_t)col1 * 64 + 32 + g * 8);
      f32x4 acc0 = {0.f, 0.f, 0.f, 0.f}, acc1 = {0.f, 0.f, 0.f, 0.f};
      acc0 = __builtin_amdgcn_mfma_f32_16x16x32_bf16(aq0, bka0, acc0, 0, 0, 0);
      acc0 = __builtin_amdgcn_mfma_f32_16x16x32_bf16(aq1, bka1, acc0, 0, 0, 0);
      acc1 = __builtin_amdgcn_mfma_f32_16x16x32_bf16(aq0, bkb0, acc1, 0, 0, 0);
      acc1 = __builtin_amdgcn_mfma_f32_16x16x32_bf16(aq1, bkb1, acc1, 0, 0, 0);
      int wi = c0 >> 6;
      int bit0 = c0 & 32;
#pragma unroll
      for (int r = 0; r < 4; ++r) {
        int qr = q0 + g * 4 + r;
        uint64_t w = (qr < L_) ? wmb[(size_t)qr * 11 + wi] : ~0ull;
        float pv0 = ((w >> (bit0 + lid)) & 1) ? 0.0f : __expf(acc0[r] * SCALE_);
        float pv1 = ((w >> (bit0 + 16 + lid)) & 1) ? 0.0f : __expf(acc1[r] * SCALE_);
        rs[r] += pv0 + pv1;
        preg[it * 4 + r] = pkbf(pv0, pv1);
      }
    }
  }
#pragma unroll
  for (int off = 8; off >= 1; off >>= 1)
#pragma unroll
    for (int r = 0; r < 4; ++r) rs[r] += __shfl_xor(rs[r], off, 64);
  if (lid == 0) {
#pragma unroll
    for (int r = 0; r < 4; ++r) sums[wave * 16 + g * 4 + r] = rs[r];
  }
  __syncthreads();
  float invr[4];
#pragma unroll
  for (int r = 0; r < 4; ++r) {
    int row = g * 4 + r;
    float s = 0.f;
#pragma unroll
    for (int ww = 0; ww < 8; ++ww) s += sums[ww * 16 + row];
    invr[r] = (s > 0.f) ? 1.0f / s : 0.0f;
  }
  int orow = t >> 5;
  int qrT = q0 + orow;
  bool rowok = (qrT < L_);
  const size_t rowb = (size_t)bh * L_ * NW_ + (size_t)(rowok ? qrT : 0) * NW_;
  int c8 = (t & 31) * 8;
  f32x4 vacc[4];
  f32x4 z4 = {0.f, 0.f, 0.f, 0.f};
#pragma unroll
  for (int dg = 0; dg < 4; ++dg) vacc[dg] = z4;
#pragma unroll
  for (int it = 0; it < 3; ++it) {
    float* sbuf = &strip2[it & 1][0][0];
    int p = it * 8 + wave;
    bool act = (p < 22);
    int mb0 = it * 256;
    if (act) {
#pragma unroll
      for (int r = 0; r < 4; ++r) {
        uint32_t u = preg[it * 4 + r];
        sbuf[(g * 4 + r) * 257 + wave * 32 + lid] = upk_lo(u) * invr[r];
        sbuf[(g * 4 + r) * 257 + wave * 32 + 16 + lid] = upk_hi(u) * invr[r];
      }
    }
    __syncthreads();
    int col = mb0 + c8;
    if (rowok) {
#pragma unroll
      for (int pr = 0; pr < 4; ++pr) {
        int cc = c8 + pr * 2;
        if (col + pr * 2 + 1 < NW_) {
          float2 o2 = make_float2(sbuf[orow * 257 + cc], sbuf[orow * 257 + cc + 1]);
          *reinterpret_cast<float2*>(OP + rowb + col + pr * 2) = o2;
        }
      }
    }
    if (act) {
      bf16x8 af;
#pragma unroll
      for (int e = 0; e < 8; ++e) af[e] = (bf16)sbuf[lid * 257 + wave * 32 + g * 8 + e];
#pragma unroll
      for (int dg = 0; dg < 4; ++dg) {
        bf16x8 bv8 = *reinterpret_cast<const bf16x8*>(vtg + (size_t)(dg * 16 + lid) * NWP_ + mb0 + wave * 32 + g * 8);
        vacc[dg] = __builtin_amdgcn_mfma_f32_16x16x32_bf16(af, bv8, vacc[dg], 0, 0, 0);
      }
    }
  }
  __syncthreads();
  float* red = &strip2[0][0][0];
#pragma unroll
  for (int wsel = 0; wsel < 8; ++wsel) {
    if (wave == wsel) {
#pragma unroll
      for (int dg = 0; dg < 4; ++dg)
#pragma unroll
        for (int r = 0; r < 4; ++r) {
          if (wsel == 0) red[(g * 4 + r) * 257 + dg * 16 + lid] = vacc[dg][r];
          else           red[(g * 4 + r) * 257 + dg * 16 + lid] += vacc[dg][r];
        }
    }
    __syncthreads();
  }
  float* ob = OV + (((size_t)b * 16 + 8 + h) * L_) * 64;
  for (int idx = t; idx < 1024; idx += 512) {
    int r = idx >> 6, d = idx & 63;
    int qr = q0 + r;
    if (qr < L_) ob[(size_t)qr * 64 + d] = red[r * 257 + d];
  }
}

extern "C" void kernel_launch(void* const* d_in, const int* in_sizes, int n_in,
                              void* d_out, int out_size, void* d_ws, size_t ws_size,
                              hipStream_t stream) {
  (void)in_sizes; (void)n_in; (void)out_size; (void)ws_size;
  const float* x    = (const float*)d_in[0];
  const float* mask = (const float*)d_in[1];
  const float* Wq   = (const float*)d_in[2];
  const float* bq   = (const float*)d_in[3];
  const float* Wk   = (const float*)d_in[4];
  const float* bk   = (const float*)d_in[5];
  const float* Wv   = (const float*)d_in[6];
  const float* bv   = (const float*)d_in[7];

  char* ws = (char*)d_ws;
  bf16* qbb     = (bf16*)(ws + 0);            // 8,380,416
  bf16* kgb     = (bf16*)(ws + 8380416);      // 4,194,304
  bf16* vgT     = (bf16*)(ws + 12574720);     // 4,194,304 (V^T [bh][d][m])
  bf16* klb     = (bf16*)(ws + 16769024);     // 1,441,792
  bf16* vlT     = (bf16*)(ws + 18210816);     // 1,441,792 (V^T local)
  uint64_t* gm  = (uint64_t*)(ws + 19652608); // 1,047,552
  uint64_t* wm  = (uint64_t*)(ws + 20700160); // 360,096
  bf16* xbb     = (bf16*)(ws + 21060256);     // 8,380,416 (x in bf16)
  bf16* wqb     = (bf16*)(ws + 29440672);     // 2,097,152 (Wq in bf16)

  float* out    = (float*)d_out;
  float* o_vall = out;                 // (2,16,2046,64)
  float* o_pg   = out + 4190208;       // (2,8,2046,2046)
  float* o_pl   = out + 71168064;      // (2,8,2046,682)

  cast4<<<4092, 256, 0, stream>>>(x, xbb, 4190208);
  cast4<<<1024, 256, 0, stream>>>(Wq, wqb, 1048576);
  qgemm_t<<<dim3(64, 8), 256, 0, stream>>>(xbb, wqb, bq, qbb);
  proj_g32<<<dim3(32, 16), 256, 0, stream>>>(x, Wk, bk, Wv, bv, kgb, vgT);
  proj_l32<<<dim3(11, 16), 256, 0, stream>>>(x, Wk, bk, Wv, bv, klb, vlT);
  maskprep<<<1023, 256, 0, stream>>>(mask, gm, wm);

  attn_gf<<<dim3(128, 16), 512, 0, stream>>>(qbb, kgb, vgT, gm, o_pg, o_vall);
  attn_lf<<<dim3(128, 16), 512, 0, stream>>>(qbb, klb, vlT, wm, o_pl, o_vall);
}